// Round 4
// baseline (187.481 us; speedup 1.0000x reference)
//
#include <hip/hip_runtime.h>

typedef unsigned short u16;
typedef unsigned int u32;
typedef __attribute__((ext_vector_type(8))) short bf16x8;
typedef __attribute__((ext_vector_type(4))) float f32x4;
typedef __attribute__((ext_vector_type(4))) u32 u32x4;
typedef __attribute__((ext_vector_type(2))) u32 u32x2;

__device__ __forceinline__ u16 f2bf(float f) {
  u32 u = __builtin_bit_cast(u32, f);
  return (u16)((u + 0x7FFFu + ((u >> 16) & 1u)) >> 16);
}
__device__ __forceinline__ float bf2f(u16 b) {
  return __builtin_bit_cast(float, (u32)b << 16);
}

__device__ __forceinline__ float fexp2(float x) {
#if __has_builtin(__builtin_amdgcn_exp2f)
  return __builtin_amdgcn_exp2f(x);
#else
  return __expf(x * 0.6931471805599453f);
#endif
}

__device__ __forceinline__ void lds_async16(const void* g, void* l) {
  auto gp = reinterpret_cast<const __attribute__((address_space(1))) u32*>(
      reinterpret_cast<uintptr_t>(g));
  auto lp = reinterpret_cast<__attribute__((address_space(3))) u32*>(
      reinterpret_cast<uintptr_t>(l));
  __builtin_amdgcn_global_load_lds(gp, lp, 16, 0, 0);
}

// ---------------- fp32 -> bf16 convert (vec4) ----------------
__global__ void cvt_kernel(const float* __restrict__ in, u16* __restrict__ out, int n4) {
  int i = blockIdx.x * 256 + threadIdx.x;
  if (i < n4) {
    f32x4 v = *(const f32x4*)(in + (size_t)i * 4);
    u32x2 o;
    o[0] = (u32)f2bf(v[0]) | ((u32)f2bf(v[1]) << 16);
    o[1] = (u32)f2bf(v[2]) | ((u32)f2bf(v[3]) << 16);
    *(u32x2*)(out + (size_t)i * 4) = o;
  }
}

// two small weight converts in one launch (block 192 is exactly the boundary)
__global__ void cvt2_kernel(const float* __restrict__ a, const float* __restrict__ b,
                            u16* __restrict__ oa, u16* __restrict__ ob, int na4, int nb4) {
  int i = blockIdx.x * 256 + threadIdx.x;
  const float* src;
  u16* dst;
  int idx;
  if (i < na4) {
    src = a; dst = oa; idx = i;
  } else {
    idx = i - na4;
    if (idx >= nb4) return;
    src = b; dst = ob;
  }
  f32x4 v = *(const f32x4*)(src + (size_t)idx * 4);
  u32x2 o;
  o[0] = (u32)f2bf(v[0]) | ((u32)f2bf(v[1]) << 16);
  o[1] = (u32)f2bf(v[2]) | ((u32)f2bf(v[3]) << 16);
  *(u32x2*)(dst + (size_t)idx * 4) = o;
}

// ---------------- GEMM: C[m][n] = sum_k A[m][k]*B[n][k] + bias[n] ----------------
// EXACT round-4 version (proven passing). Round-5/6 operand swap mfma(bfr, af)
// with a vectorized epilogue produced absmax 1.01 in two clean A/B runs —
// reverted permanently. Do NOT swap the mfma operand order here.
template <bool OUT_BF16>
__global__ __launch_bounds__(256) void gemm_bt_kernel(
    const u16* __restrict__ A, const u16* __restrict__ B,
    const float* __restrict__ bias, void* __restrict__ C,
    int M, int N, int K) {
  __shared__ u16 sA[128 * 32];
  __shared__ u16 sB[128 * 32];
  const int tid = threadIdx.x;
  const int m0 = blockIdx.x * 128;
  const int n0 = blockIdx.y * 128;
  const int w = tid >> 6;
  const int lane = tid & 63;
  const int wr = (w >> 1) * 64;
  const int wc = (w & 1) * 64;
  const int lm = lane & 15;
  const int lk = (lane >> 4) * 8;

  f32x4 acc[4][4] = {};

  const int srow = tid >> 2;
  const int ssub = (tid & 3) * 8;
  const u16* Ag = A + (size_t)(m0 + srow) * K + ssub;
  const u16* Bg = B + (size_t)(n0 + srow) * K + ssub;
  const size_t rstep = (size_t)64 * K;

  for (int k0 = 0; k0 < K; k0 += 32) {
    __syncthreads();
    lds_async16(Ag + k0, &sA[tid * 8]);
    lds_async16(Ag + rstep + k0, &sA[2048 + tid * 8]);
    lds_async16(Bg + k0, &sB[tid * 8]);
    lds_async16(Bg + rstep + k0, &sB[2048 + tid * 8]);
    __syncthreads();
    bf16x8 af[4], bfr[4];
#pragma unroll
    for (int i = 0; i < 4; ++i)
      af[i] = *(const bf16x8*)&sA[(wr + i * 16 + lm) * 32 + lk];
#pragma unroll
    for (int j = 0; j < 4; ++j)
      bfr[j] = *(const bf16x8*)&sB[(wc + j * 16 + lm) * 32 + lk];
#pragma unroll
    for (int i = 0; i < 4; ++i)
#pragma unroll
      for (int j = 0; j < 4; ++j)
        acc[i][j] = __builtin_amdgcn_mfma_f32_16x16x32_bf16(af[i], bfr[j], acc[i][j], 0, 0, 0);
  }

  const int r0 = (lane >> 4) * 4;
#pragma unroll
  for (int j = 0; j < 4; ++j) {
    const int n = n0 + wc + j * 16 + lm;
    const float bv = bias[n];
#pragma unroll
    for (int i = 0; i < 4; ++i) {
#pragma unroll
      for (int r = 0; r < 4; ++r) {
        const int m = m0 + wr + i * 16 + r0 + r;
        float v = acc[i][j][r] + bv;
        if (OUT_BF16)
          ((u16*)C)[(size_t)m * N + n] = f2bf(v);
        else
          ((float*)C)[(size_t)m * N + n] = v;
      }
    }
  }
}

// ---------------- fused per-(block,head) attention ----------------
// qkv: 33792 x 768 bf16 (q|k|v each 256 cols). o_ws: (256 blocks x 256 rows x 256 f) bf16.
// S^T compute (mfma(K,Q)) so P regs are 4 consecutive j -> b64 LDS writes.
// PV done in two 32-row halves; per-wave P tile 32x40 u16.
// LDS = sVt 16896 + sP 10240 = 27136 B (6 blocks/CU by LDS).
// Round-2 proven set (44.9us): sVt col XOR-swizzle; v_cvt_pk_bf16_f32 packing;
// denominator via mfma(P, ones) in lacc (lands at exact epilogue row lg*4+r);
// 1-deep K prefetch; setprio around PV; single sP + WAR fence.
// Round-3 POST-MORTEM: sP hf-double-buffer (37376 B LDS) dropped residency
// 5->4 blocks/CU (occupancy 31->24%) and REGRESSED 44.9->48.0. The fence is
// NOT the dominant serializer; occupancy is. Do not re-add the dbuf.
// Round-4 changes:
//  - sP column XOR by row-bit3 (xk = (lm>>3)<<3 u16) on write AND read.
//    Old banks: writes dword row*20 + ct*8+lg*2, reads row*20 + lg*4 with
//    8*20 == 0 mod 32 -> lm/lm+8 lanes fully collide (4-way reads). Bit-3
//    XOR moves lm>=8 lanes to disjoint dword ranges; 8-u16 block XOR keeps
//    both b64 writes and b128 reads contiguous/aligned. Residual 3.67M
//    conflict cycles (~13% of runtime) should drop ~2-3x.
//  - V fragments prefetched one ch ahead into regs (vfc/vfn): ~120cy LDS
//    latency off the PV head (kept from r3; independent of the dbuf).
// launch_bounds(256,2): (256,4) spilled catastrophically (r2, old structure).
// `#pragma unroll 1` on the ch loop is load-bearing: full unroll hoists all
// kf loads and spills (r3).
__global__ __launch_bounds__(256, 2) void attn_kernel(const u16* __restrict__ qkv,
                                                      u16* __restrict__ o_ws) {
  __shared__ u16 sVt[32 * 264];   // V transposed, stride 264 u16, cols XOR-swizzled
  __shared__ u16 sP[4 * 32 * 40]; // per-wave P half-tile: 32 rows x 40 u16

  const int bid = blockIdx.x;
  const int n = bid >> 3;
  const int h = bid & 7;
  const int rowbase = (n >> 5) * 4224 + (n & 31) * 128;
  const int tid = threadIdx.x;
  const int w = tid >> 6;
  const int lane = tid & 63;
  const int lm = lane & 15;
  const int lg = lane >> 4;

  // stage V transposed for this head: V[j][d] -> sVt[d*264 + (j ^ ((d>>3)<<4))]
#pragma unroll
  for (int it = 0; it < 4; ++it) {
    int c = it * 256 + tid;
    int row = c >> 2;
    int sub = (c & 3) * 8;
    int rsw = row ^ ((sub >> 3) << 4);   // swizzled column; (d>>3) is sub>>3 for all 8 d
    const u16* gv = qkv + (size_t)(rowbase + row) * 768 + 512 + h * 32 + sub;
    u32x4 vv = *(const u32x4*)gv;
#pragma unroll
    for (int q = 0; q < 4; ++q) {
      sVt[(sub + 2 * q) * 264 + rsw] = (u16)(vv[q] & 0xFFFFu);
      sVt[(sub + 2 * q + 1) * 264 + rsw] = (u16)(vv[q] >> 16);
    }
  }

  // Q fragments straight from global (wave-private rows; 16 rows x 64B contiguous)
  bf16x8 qf[4];
#pragma unroll
  for (int rt = 0; rt < 4; ++rt) {
    int row = rowbase + w * 64 + rt * 16 + lm;
    qf[rt] = *(const bf16x8*)(qkv + (size_t)row * 768 + h * 32 + lg * 8);
  }

  const u16* kbase = qkv + (size_t)(rowbase + lm) * 768 + 256 + h * 32 + lg * 8;

  // prime K prefetch for ch=0 (overlaps the staging barrier)
  bf16x8 kfc[2];
#pragma unroll
  for (int ct = 0; ct < 2; ++ct)
    kfc[ct] = *(const bf16x8*)(kbase + (size_t)(ct * 16) * 768);

  __syncthreads();

  // prime V prefetch for ch=0 (right after the barrier)
  bf16x8 vfc[2];
#pragma unroll
  for (int ctd = 0; ctd < 2; ++ctd) {
    int d = ctd * 16 + lm;
    vfc[ctd] = *(const bf16x8*)&sVt[d * 264 + ((lg * 8) ^ ((d >> 3) << 4))];
  }

  f32x4 oacc[4][2] = {};
  f32x4 lacc[4] = {};   // softmax denominators via mfma(P, ones)
  u16* myP = sP + w * (32 * 40);
  const float C1 = 0.25500035370494726f; // scale * log2(e)
  const float C2 = 1.4426950408889634f;  // log2(e)
  const int jq = lg * 4;
  const int D0w = w * 64;
  const int xk = (lm >> 3) << 3;  // sP bank swizzle: row-bit3 XOR, 8-u16 blocks
  const bf16x8 onesb = {(short)0x3F80, (short)0x3F80, (short)0x3F80, (short)0x3F80,
                        (short)0x3F80, (short)0x3F80, (short)0x3F80, (short)0x3F80};

#pragma unroll 1
  for (int ch = 0; ch < 8; ++ch) {
    // prefetch next chunk's K (global) and V (LDS) fragments; last iter is dead
    const int chn = (ch < 7) ? ch + 1 : 7;
    bf16x8 kfn[2], vfn[2];
#pragma unroll
    for (int ct = 0; ct < 2; ++ct)
      kfn[ct] = *(const bf16x8*)(kbase + (size_t)(chn * 32 + ct * 16) * 768);
#pragma unroll
    for (int ctd = 0; ctd < 2; ++ctd) {
      int d = ctd * 16 + lm;
      vfn[ctd] = *(const bf16x8*)&sVt[d * 264 + ((chn * 32 + lg * 8) ^ ((d >> 3) << 4))];
    }

#pragma unroll
    for (int hf = 0; hf < 2; ++hf) {
#pragma unroll
      for (int ct = 0; ct < 2; ++ct) {
#pragma unroll
        for (int rl = 0; rl < 2; ++rl) {
          const int rt = hf * 2 + rl;
          f32x4 s = __builtin_amdgcn_mfma_f32_16x16x32_bf16(kfc[ct], qf[rt], f32x4{0.f, 0.f, 0.f, 0.f}, 0, 0, 0);
          const int D0 = D0w + rt * 16 - (ch * 32 + ct * 16); // wave-uniform
          float p0, p1, p2, p3;
          if (D0 >= 16 && D0 <= 112) {        // fully in-band: +1 bias
            p0 = fexp2(__builtin_fmaf(s[0], C1, C2));
            p1 = fexp2(__builtin_fmaf(s[1], C1, C2));
            p2 = fexp2(__builtin_fmaf(s[2], C1, C2));
            p3 = fexp2(__builtin_fmaf(s[3], C1, C2));
          } else if (D0 == 0) {               // diagonal: in-band iff lm >= jq+r
            p0 = fexp2(__builtin_fmaf(s[0], C1, (lm >= jq + 0) ? C2 : 0.0f));
            p1 = fexp2(__builtin_fmaf(s[1], C1, (lm >= jq + 1) ? C2 : 0.0f));
            p2 = fexp2(__builtin_fmaf(s[2], C1, (lm >= jq + 2) ? C2 : 0.0f));
            p3 = fexp2(__builtin_fmaf(s[3], C1, (lm >= jq + 3) ? C2 : 0.0f));
          } else if (D0 == 128) {             // far edge: in-band iff lm < jq+r
            p0 = fexp2(__builtin_fmaf(s[0], C1, (lm < jq + 0) ? C2 : 0.0f));
            p1 = fexp2(__builtin_fmaf(s[1], C1, (lm < jq + 1) ? C2 : 0.0f));
            p2 = fexp2(__builtin_fmaf(s[2], C1, (lm < jq + 2) ? C2 : 0.0f));
            p3 = fexp2(__builtin_fmaf(s[3], C1, (lm < jq + 3) ? C2 : 0.0f));
          } else {                            // fully out of band: no bias
            p0 = fexp2(s[0] * C1);
            p1 = fexp2(s[1] * C1);
            p2 = fexp2(s[2] * C1);
            p3 = fexp2(s[3] * C1);
          }
          u32 a0, a1;
          asm("v_cvt_pk_bf16_f32 %0, %1, %2" : "=v"(a0) : "v"(p0), "v"(p1));
          asm("v_cvt_pk_bf16_f32 %0, %1, %2" : "=v"(a1) : "v"(p2), "v"(p3));
          u32x2 pk;
          pk[0] = a0;
          pk[1] = a1;
          *(u32x2*)&myP[(rl * 16 + lm) * 40 + ((ct * 16 + jq) ^ xk)] = pk;
        }
      }
      // O(half) += P(half) * Vc ; lsum(half) += P(half) . 1  (wave-private P)
      bf16x8 pf[2];
#pragma unroll
      for (int rl = 0; rl < 2; ++rl)
        pf[rl] = *(const bf16x8*)&myP[(rl * 16 + lm) * 40 + ((lg * 8) ^ xk)];
      // pin WAR order: these reads must precede the next half's overwrites
      __asm__ __volatile__("" ::: "memory");
      __builtin_amdgcn_s_setprio(1);
#pragma unroll
      for (int rl = 0; rl < 2; ++rl) {
#pragma unroll
        for (int ctd = 0; ctd < 2; ++ctd)
          oacc[hf * 2 + rl][ctd] =
              __builtin_amdgcn_mfma_f32_16x16x32_bf16(pf[rl], vfc[ctd], oacc[hf * 2 + rl][ctd], 0, 0, 0);
        lacc[hf * 2 + rl] =
            __builtin_amdgcn_mfma_f32_16x16x32_bf16(pf[rl], onesb, lacc[hf * 2 + rl], 0, 0, 0);
      }
      __builtin_amdgcn_s_setprio(0);
    }
    kfc[0] = kfn[0];
    kfc[1] = kfn[1];
    vfc[0] = vfn[0];
    vfc[1] = vfn[1];
  }

  // normalize + store; lacc[rt][r] holds the full denominator for row
  // i = rt*16 + lg*4 + r (C/D layout row = lg*4+r), exactly the epilogue row.
#pragma unroll
  for (int rt = 0; rt < 4; ++rt) {
#pragma unroll
    for (int r = 0; r < 4; ++r) {
      float inv = 1.0f / lacc[rt][r];
      int i_g = w * 64 + rt * 16 + jq + r;
#pragma unroll
      for (int ctd = 0; ctd < 2; ++ctd) {
        float v = oacc[rt][ctd][r] * inv;
        u32 u = __builtin_bit_cast(u32, v) + 0x8000u;
        o_ws[((size_t)(n * 256 + i_g)) * 256 + h * 32 + ctd * 16 + lm] = (u16)(u >> 16);
      }
    }
  }
}

// ---------------- overlap-add combine: oc[t] = sum(covering o_ws)/cnt ----------------
__global__ void combine_kernel(const u16* __restrict__ o_ws, u16* __restrict__ oc) {
  int gid = blockIdx.x * 256 + threadIdx.x;
  int m = gid >> 5;             // global row (bc*4224 + t)
  int f0 = (gid & 31) << 3;     // 8 features per thread
  int bc = m / 4224;
  int t = m - bc * 4224;
  int i0 = t >> 7;
  float a[8] = {0.f, 0.f, 0.f, 0.f, 0.f, 0.f, 0.f, 0.f};
  if (i0 <= 31) {
    const u16* p = o_ws + ((size_t)((bc * 32 + i0) * 256 + (t - (i0 << 7)))) * 256 + f0;
    u32x4 v = *(const u32x4*)p;
#pragma unroll
    for (int q = 0; q < 4; ++q) {
      a[2 * q] += bf2f((u16)(v[q] & 0xFFFFu));
      a[2 * q + 1] += bf2f((u16)(v[q] >> 16));
    }
  }
  if (i0 >= 1) {
    int i1 = i0 - 1;
    const u16* p = o_ws + ((size_t)((bc * 32 + i1) * 256 + (t - (i1 << 7)))) * 256 + f0;
    u32x4 v = *(const u32x4*)p;
#pragma unroll
    for (int q = 0; q < 4; ++q) {
      a[2 * q] += bf2f((u16)(v[q] & 0xFFFFu));
      a[2 * q + 1] += bf2f((u16)(v[q] >> 16));
    }
  }
  float sc = (i0 >= 1 && i0 <= 31) ? 0.5f : 1.0f;
  u32x2 o;
  o[0] = (u32)f2bf(a[0] * sc) | ((u32)f2bf(a[1] * sc) << 16);
  o[1] = (u32)f2bf(a[2] * sc) | ((u32)f2bf(a[3] * sc) << 16);
  u32x2 o2;
  o2[0] = (u32)f2bf(a[4] * sc) | ((u32)f2bf(a[5] * sc) << 16);
  o2[1] = (u32)f2bf(a[6] * sc) | ((u32)f2bf(a[7] * sc) << 16);
  u16* dst = oc + (size_t)m * 256 + f0;
  *(u32x2*)dst = o;
  *(u32x2*)(dst + 4) = o2;
}

extern "C" void kernel_launch(void* const* d_in, const int* in_sizes, int n_in,
                              void* d_out, int out_size, void* d_ws, size_t ws_size,
                              hipStream_t stream) {
  const float* x = (const float*)d_in[0];
  const float* w_in = (const float*)d_in[1];
  const float* b_in = (const float*)d_in[2];
  const float* w_out = (const float*)d_in[3];
  const float* b_out = (const float*)d_in[4];
  float* y = (float*)d_out;
  char* ws = (char*)d_ws;

  // workspace layout (bytes)
  u16* qkv = (u16*)(ws);                   // 33792*768*2   = 51,904,512
  u16* xbf = (u16*)(ws + 51904512);        // 33792*256*2   = 17,301,504 (reused as oc)
  u16* ows = (u16*)(ws + 69206016);        // 256*256*256*2 = 33,554,432
  u16* winb = (u16*)(ws + 102760448);      // 768*256*2     = 393,216
  u16* woutb = (u16*)(ws + 103153664);     // 256*256*2     = 131,072  (end 103,284,736)

  cvt_kernel<<<8448, 256, 0, stream>>>(x, xbf, 2162688);
  cvt2_kernel<<<256, 256, 0, stream>>>(w_in, w_out, winb, woutb, 49152, 16384);

  // qkv = x @ w_in^T + b_in  (once per row; overlapping blocks share rows)
  gemm_bt_kernel<true><<<dim3(264, 6), 256, 0, stream>>>(xbf, winb, b_in, qkv, 33792, 768, 256);

  // per-(block, head) attention
  attn_kernel<<<2048, 256, 0, stream>>>(qkv, ows);

  // overlap-add + count division (commutes with the linear w_out projection)
  combine_kernel<<<4224, 256, 0, stream>>>(ows, xbf);

  // y = oc @ w_out^T + b_out
  gemm_bt_kernel<false><<<dim3(264, 2), 256, 0, stream>>>(xbf, woutb, b_out, y, 33792, 256, 256);
}

// Round 6
// 179.645 us; speedup vs baseline: 1.0436x; 1.0436x over previous
//
#include <hip/hip_runtime.h>

typedef unsigned short u16;
typedef unsigned int u32;
typedef __attribute__((ext_vector_type(8))) short bf16x8;
typedef __attribute__((ext_vector_type(4))) float f32x4;
typedef __attribute__((ext_vector_type(4))) u32 u32x4;
typedef __attribute__((ext_vector_type(2))) u32 u32x2;

__device__ __forceinline__ u16 f2bf(float f) {
  u32 u = __builtin_bit_cast(u32, f);
  return (u16)((u + 0x7FFFu + ((u >> 16) & 1u)) >> 16);
}
__device__ __forceinline__ float bf2f(u16 b) {
  return __builtin_bit_cast(float, (u32)b << 16);
}

// v_cvt_pk_bf16_f32 = RNE, bitwise-identical to f2bf for finite inputs.
__device__ __forceinline__ u32 cvtpk(float lo, float hi) {
  u32 r;
  asm("v_cvt_pk_bf16_f32 %0, %1, %2" : "=v"(r) : "v"(lo), "v"(hi));
  return r;
}

__device__ __forceinline__ float fexp2(float x) {
#if __has_builtin(__builtin_amdgcn_exp2f)
  return __builtin_amdgcn_exp2f(x);
#else
  return __expf(x * 0.6931471805599453f);
#endif
}

__device__ __forceinline__ void lds_async16(const void* g, void* l) {
  auto gp = reinterpret_cast<const __attribute__((address_space(1))) u32*>(
      reinterpret_cast<uintptr_t>(g));
  auto lp = reinterpret_cast<__attribute__((address_space(3))) u32*>(
      reinterpret_cast<uintptr_t>(l));
  __builtin_amdgcn_global_load_lds(gp, lp, 16, 0, 0);
}

// two small weight converts in one launch
__global__ void cvt2_kernel(const float* __restrict__ a, const float* __restrict__ b,
                            u16* __restrict__ oa, u16* __restrict__ ob, int na4, int nb4) {
  int i = blockIdx.x * 256 + threadIdx.x;
  const float* src;
  u16* dst;
  int idx;
  if (i < na4) {
    src = a; dst = oa; idx = i;
  } else {
    idx = i - na4;
    if (idx >= nb4) return;
    src = b; dst = ob;
  }
  f32x4 v = *(const f32x4*)(src + (size_t)idx * 4);
  u32x2 o;
  o[0] = (u32)f2bf(v[0]) | ((u32)f2bf(v[1]) << 16);
  o[1] = (u32)f2bf(v[2]) | ((u32)f2bf(v[3]) << 16);
  *(u32x2*)(dst + (size_t)idx * 4) = o;
}

// ---------------- GEMM: C[m][n] = sum_k A[m][k]*B[n][k] + bias[n] ----------------
// EXACT round-4 version (proven passing) for the fragment/mfma/epilogue path.
// Round-5/6 (old session) operand swap mfma(bfr, af) produced absmax 1.01 —
// reverted permanently. Do NOT swap the mfma operand order here.
// Round-6 (this session): A_F32 template path — A staged from f32 global via
// reg-load + v_cvt_pk_bf16_f32 (RNE == f2bf, so bf16 values are bitwise
// identical to the old cvt_kernel output) + ds_write_b128. The f32 loads are
// issued BEFORE the WAR barrier so HBM latency overlaps the previous k-step's
// MFMAs. B-side staging and everything downstream untouched.
template <bool OUT_BF16, bool A_F32>
__global__ __launch_bounds__(256) void gemm_bt_kernel(
    const void* __restrict__ A, const u16* __restrict__ B,
    const float* __restrict__ bias, void* __restrict__ C,
    int M, int N, int K) {
  __shared__ u16 sA[128 * 32];
  __shared__ u16 sB[128 * 32];
  const int tid = threadIdx.x;
  const int m0 = blockIdx.x * 128;
  const int n0 = blockIdx.y * 128;
  const int w = tid >> 6;
  const int lane = tid & 63;
  const int wr = (w >> 1) * 64;
  const int wc = (w & 1) * 64;
  const int lm = lane & 15;
  const int lk = (lane >> 4) * 8;

  f32x4 acc[4][4] = {};

  const int srow = tid >> 2;
  const int ssub = (tid & 3) * 8;
  const u16* Ag = (const u16*)A + (size_t)(m0 + srow) * K + ssub;
  const float* Agf = (const float*)A + (size_t)(m0 + srow) * K + ssub;
  const u16* Bg = B + (size_t)(n0 + srow) * K + ssub;
  const size_t rstep = (size_t)64 * K;

  for (int k0 = 0; k0 < K; k0 += 32) {
    f32x4 a00, a01, a10, a11;
    if constexpr (A_F32) {
      // global f32 loads issued before the barrier: overlap prev step's MFMAs
      a00 = *(const f32x4*)(Agf + k0);
      a01 = *(const f32x4*)(Agf + k0 + 4);
      a10 = *(const f32x4*)(Agf + rstep + k0);
      a11 = *(const f32x4*)(Agf + rstep + k0 + 4);
    }
    __syncthreads();
    if constexpr (A_F32) {
      u32x4 w0, w1;
      w0[0] = cvtpk(a00[0], a00[1]); w0[1] = cvtpk(a00[2], a00[3]);
      w0[2] = cvtpk(a01[0], a01[1]); w0[3] = cvtpk(a01[2], a01[3]);
      w1[0] = cvtpk(a10[0], a10[1]); w1[1] = cvtpk(a10[2], a10[3]);
      w1[2] = cvtpk(a11[0], a11[1]); w1[3] = cvtpk(a11[2], a11[3]);
      *(u32x4*)&sA[tid * 8] = w0;
      *(u32x4*)&sA[2048 + tid * 8] = w1;
    } else {
      lds_async16(Ag + k0, &sA[tid * 8]);
      lds_async16(Ag + rstep + k0, &sA[2048 + tid * 8]);
    }
    lds_async16(Bg + k0, &sB[tid * 8]);
    lds_async16(Bg + rstep + k0, &sB[2048 + tid * 8]);
    __syncthreads();
    bf16x8 af[4], bfr[4];
#pragma unroll
    for (int i = 0; i < 4; ++i)
      af[i] = *(const bf16x8*)&sA[(wr + i * 16 + lm) * 32 + lk];
#pragma unroll
    for (int j = 0; j < 4; ++j)
      bfr[j] = *(const bf16x8*)&sB[(wc + j * 16 + lm) * 32 + lk];
#pragma unroll
    for (int i = 0; i < 4; ++i)
#pragma unroll
      for (int j = 0; j < 4; ++j)
        acc[i][j] = __builtin_amdgcn_mfma_f32_16x16x32_bf16(af[i], bfr[j], acc[i][j], 0, 0, 0);
  }

  const int r0 = (lane >> 4) * 4;
#pragma unroll
  for (int j = 0; j < 4; ++j) {
    const int n = n0 + wc + j * 16 + lm;
    const float bv = bias[n];
#pragma unroll
    for (int i = 0; i < 4; ++i) {
#pragma unroll
      for (int r = 0; r < 4; ++r) {
        const int m = m0 + wr + i * 16 + r0 + r;
        float v = acc[i][j][r] + bv;
        if (OUT_BF16)
          ((u16*)C)[(size_t)m * N + n] = f2bf(v);
        else
          ((float*)C)[(size_t)m * N + n] = v;
      }
    }
  }
}

// ---------------- fused per-(block,head) attention ----------------
// ROUND-2 EXACT SOURCE (proven 44.9us, VGPR 64, occ 31%). Do not "improve"
// without a within-session A/B.
// LEDGER (measured):
//  r2 44.9us: sVt col XOR-swizzle; cvt_pk packing; denominator via
//    mfma(P, ones); 1-deep K prefetch; setprio; single sP + WAR fence.
//  r3 48.0us REGRESSED: sP hf-dbuf + V-reg-prefetch -> VGPR 68 crossed the
//    64-VGPR allocation cliff (8->7 waves/SIMD), occ 31->24%.
//  r4 48.0us: sP-XOR changed conflict count by exactly 0 (3735552) ->
//    conflicts are NOT sP; V-prefetch's +4 VGPR was the whole r3 regression.
//    LESSON: stay at VGPR <= 64.
//  r5 FAILED (absmax 0.19): K-row re-tiling (j=(lm>>2)*8+ct*4+(lm&3)) to keep
//    the PV A-fragment in regs. Algebra checks under all GEMM-pinned fragment
//    mappings incl. the sigma-permutation freedom; hardware disagrees. OPEN
//    MYSTERY — do not retry without disasm evidence.
// launch_bounds(256,2): (256,4) spilled catastrophically. `#pragma unroll 1`
// on the ch loop is load-bearing: full unroll hoists all kf loads and spills.
// The asm memory fence pins the P-tile read -> overwrite (WAR) order.
__global__ __launch_bounds__(256, 2) void attn_kernel(const u16* __restrict__ qkv,
                                                      u16* __restrict__ o_ws) {
  __shared__ u16 sVt[32 * 264];   // V transposed, stride 264 u16, cols XOR-swizzled
  __shared__ u16 sP[4 * 32 * 40]; // per-wave P half-tile: 32 rows x 40 u16

  const int bid = blockIdx.x;
  const int n = bid >> 3;
  const int h = bid & 7;
  const int rowbase = (n >> 5) * 4224 + (n & 31) * 128;
  const int tid = threadIdx.x;
  const int w = tid >> 6;
  const int lane = tid & 63;
  const int lm = lane & 15;
  const int lg = lane >> 4;

  // stage V transposed for this head: V[j][d] -> sVt[d*264 + (j ^ ((d>>3)<<4))]
#pragma unroll
  for (int it = 0; it < 4; ++it) {
    int c = it * 256 + tid;
    int row = c >> 2;
    int sub = (c & 3) * 8;
    int rsw = row ^ ((sub >> 3) << 4);   // swizzled column; (d>>3) is sub>>3 for all 8 d
    const u16* gv = qkv + (size_t)(rowbase + row) * 768 + 512 + h * 32 + sub;
    u32x4 vv = *(const u32x4*)gv;
#pragma unroll
    for (int q = 0; q < 4; ++q) {
      sVt[(sub + 2 * q) * 264 + rsw] = (u16)(vv[q] & 0xFFFFu);
      sVt[(sub + 2 * q + 1) * 264 + rsw] = (u16)(vv[q] >> 16);
    }
  }

  // Q fragments straight from global (wave-private rows; 16 rows x 64B contiguous)
  bf16x8 qf[4];
#pragma unroll
  for (int rt = 0; rt < 4; ++rt) {
    int row = rowbase + w * 64 + rt * 16 + lm;
    qf[rt] = *(const bf16x8*)(qkv + (size_t)row * 768 + h * 32 + lg * 8);
  }

  const u16* kbase = qkv + (size_t)(rowbase + lm) * 768 + 256 + h * 32 + lg * 8;

  // prime K prefetch for ch=0 (overlaps the staging barrier)
  bf16x8 kfc[2];
#pragma unroll
  for (int ct = 0; ct < 2; ++ct)
    kfc[ct] = *(const bf16x8*)(kbase + (size_t)(ct * 16) * 768);

  __syncthreads();

  f32x4 oacc[4][2] = {};
  f32x4 lacc[4] = {};   // softmax denominators via mfma(P, ones)
  u16* myP = sP + w * (32 * 40);
  const float C1 = 0.25500035370494726f; // scale * log2(e)
  const float C2 = 1.4426950408889634f;  // log2(e)
  const int jq = lg * 4;
  const int D0w = w * 64;
  const bf16x8 onesb = {(short)0x3F80, (short)0x3F80, (short)0x3F80, (short)0x3F80,
                        (short)0x3F80, (short)0x3F80, (short)0x3F80, (short)0x3F80};

#pragma unroll 1
  for (int ch = 0; ch < 8; ++ch) {
    // prefetch next chunk's K fragments (clamped; last iter loads are dead)
    const int chn = (ch < 7) ? ch + 1 : 7;
    bf16x8 kfn[2], vf[2];
#pragma unroll
    for (int ct = 0; ct < 2; ++ct)
      kfn[ct] = *(const bf16x8*)(kbase + (size_t)(chn * 32 + ct * 16) * 768);
#pragma unroll
    for (int ctd = 0; ctd < 2; ++ctd) {
      int d = ctd * 16 + lm;
      vf[ctd] = *(const bf16x8*)&sVt[d * 264 + ((ch * 32 + lg * 8) ^ ((d >> 3) << 4))];
    }

#pragma unroll
    for (int hf = 0; hf < 2; ++hf) {
#pragma unroll
      for (int ct = 0; ct < 2; ++ct) {
#pragma unroll
        for (int rl = 0; rl < 2; ++rl) {
          const int rt = hf * 2 + rl;
          f32x4 s = __builtin_amdgcn_mfma_f32_16x16x32_bf16(kfc[ct], qf[rt], f32x4{0.f, 0.f, 0.f, 0.f}, 0, 0, 0);
          const int D0 = D0w + rt * 16 - (ch * 32 + ct * 16); // wave-uniform
          float p0, p1, p2, p3;
          if (D0 >= 16 && D0 <= 112) {        // fully in-band: +1 bias
            p0 = fexp2(__builtin_fmaf(s[0], C1, C2));
            p1 = fexp2(__builtin_fmaf(s[1], C1, C2));
            p2 = fexp2(__builtin_fmaf(s[2], C1, C2));
            p3 = fexp2(__builtin_fmaf(s[3], C1, C2));
          } else if (D0 == 0) {               // diagonal: in-band iff lm >= jq+r
            p0 = fexp2(__builtin_fmaf(s[0], C1, (lm >= jq + 0) ? C2 : 0.0f));
            p1 = fexp2(__builtin_fmaf(s[1], C1, (lm >= jq + 1) ? C2 : 0.0f));
            p2 = fexp2(__builtin_fmaf(s[2], C1, (lm >= jq + 2) ? C2 : 0.0f));
            p3 = fexp2(__builtin_fmaf(s[3], C1, (lm >= jq + 3) ? C2 : 0.0f));
          } else if (D0 == 128) {             // far edge: in-band iff lm < jq+r
            p0 = fexp2(__builtin_fmaf(s[0], C1, (lm < jq + 0) ? C2 : 0.0f));
            p1 = fexp2(__builtin_fmaf(s[1], C1, (lm < jq + 1) ? C2 : 0.0f));
            p2 = fexp2(__builtin_fmaf(s[2], C1, (lm < jq + 2) ? C2 : 0.0f));
            p3 = fexp2(__builtin_fmaf(s[3], C1, (lm < jq + 3) ? C2 : 0.0f));
          } else {                            // fully out of band: no bias
            p0 = fexp2(s[0] * C1);
            p1 = fexp2(s[1] * C1);
            p2 = fexp2(s[2] * C1);
            p3 = fexp2(s[3] * C1);
          }
          u32 a0, a1;
          asm("v_cvt_pk_bf16_f32 %0, %1, %2" : "=v"(a0) : "v"(p0), "v"(p1));
          asm("v_cvt_pk_bf16_f32 %0, %1, %2" : "=v"(a1) : "v"(p2), "v"(p3));
          u32x2 pk;
          pk[0] = a0;
          pk[1] = a1;
          *(u32x2*)&myP[(rl * 16 + lm) * 40 + ct * 16 + jq] = pk;
        }
      }
      // O(half) += P(half) * Vc ; lsum(half) += P(half) . 1  (wave-private P)
      bf16x8 pf[2];
#pragma unroll
      for (int rl = 0; rl < 2; ++rl)
        pf[rl] = *(const bf16x8*)&myP[(rl * 16 + lm) * 40 + lg * 8];
      // pin WAR order: these reads must precede the next half's overwrites
      __asm__ __volatile__("" ::: "memory");
      __builtin_amdgcn_s_setprio(1);
#pragma unroll
      for (int rl = 0; rl < 2; ++rl) {
        lacc[hf * 2 + rl] =
            __builtin_amdgcn_mfma_f32_16x16x32_bf16(pf[rl], onesb, lacc[hf * 2 + rl], 0, 0, 0);
#pragma unroll
        for (int ctd = 0; ctd < 2; ++ctd)
          oacc[hf * 2 + rl][ctd] =
              __builtin_amdgcn_mfma_f32_16x16x32_bf16(pf[rl], vf[ctd], oacc[hf * 2 + rl][ctd], 0, 0, 0);
      }
      __builtin_amdgcn_s_setprio(0);
    }
    kfc[0] = kfn[0];
    kfc[1] = kfn[1];
  }

  // normalize + store; lacc[rt][r] holds the full denominator for row
  // i = rt*16 + lg*4 + r (C/D layout row = lg*4+r), exactly the epilogue row.
#pragma unroll
  for (int rt = 0; rt < 4; ++rt) {
#pragma unroll
    for (int r = 0; r < 4; ++r) {
      float inv = 1.0f / lacc[rt][r];
      int i_g = w * 64 + rt * 16 + jq + r;
#pragma unroll
      for (int ctd = 0; ctd < 2; ++ctd) {
        float v = oacc[rt][ctd][r] * inv;
        u32 u = __builtin_bit_cast(u32, v) + 0x8000u;
        o_ws[((size_t)(n * 256 + i_g)) * 256 + h * 32 + ctd * 16 + lm] = (u16)(u >> 16);
      }
    }
  }
}

// ---------------- overlap-add combine: oc[t] = sum(covering o_ws)/cnt ----------------
__global__ void combine_kernel(const u16* __restrict__ o_ws, u16* __restrict__ oc) {
  int gid = blockIdx.x * 256 + threadIdx.x;
  int m = gid >> 5;             // global row (bc*4224 + t)
  int f0 = (gid & 31) << 3;     // 8 features per thread
  int bc = m / 4224;
  int t = m - bc * 4224;
  int i0 = t >> 7;
  float a[8] = {0.f, 0.f, 0.f, 0.f, 0.f, 0.f, 0.f, 0.f};
  if (i0 <= 31) {
    const u16* p = o_ws + ((size_t)((bc * 32 + i0) * 256 + (t - (i0 << 7)))) * 256 + f0;
    u32x4 v = *(const u32x4*)p;
#pragma unroll
    for (int q = 0; q < 4; ++q) {
      a[2 * q] += bf2f((u16)(v[q] & 0xFFFFu));
      a[2 * q + 1] += bf2f((u16)(v[q] >> 16));
    }
  }
  if (i0 >= 1) {
    int i1 = i0 - 1;
    const u16* p = o_ws + ((size_t)((bc * 32 + i1) * 256 + (t - (i1 << 7)))) * 256 + f0;
    u32x4 v = *(const u32x4*)p;
#pragma unroll
    for (int q = 0; q < 4; ++q) {
      a[2 * q] += bf2f((u16)(v[q] & 0xFFFFu));
      a[2 * q + 1] += bf2f((u16)(v[q] >> 16));
    }
  }
  float sc = (i0 >= 1 && i0 <= 31) ? 0.5f : 1.0f;
  u32x2 o;
  o[0] = (u32)f2bf(a[0] * sc) | ((u32)f2bf(a[1] * sc) << 16);
  o[1] = (u32)f2bf(a[2] * sc) | ((u32)f2bf(a[3] * sc) << 16);
  u32x2 o2;
  o2[0] = (u32)f2bf(a[4] * sc) | ((u32)f2bf(a[5] * sc) << 16);
  o2[1] = (u32)f2bf(a[6] * sc) | ((u32)f2bf(a[7] * sc) << 16);
  u16* dst = oc + (size_t)m * 256 + f0;
  *(u32x2*)dst = o;
  *(u32x2*)(dst + 4) = o2;
}

extern "C" void kernel_launch(void* const* d_in, const int* in_sizes, int n_in,
                              void* d_out, int out_size, void* d_ws, size_t ws_size,
                              hipStream_t stream) {
  const float* x = (const float*)d_in[0];
  const float* w_in = (const float*)d_in[1];
  const float* b_in = (const float*)d_in[2];
  const float* w_out = (const float*)d_in[3];
  const float* b_out = (const float*)d_in[4];
  float* y = (float*)d_out;
  char* ws = (char*)d_ws;

  // workspace layout (bytes)
  u16* qkv = (u16*)(ws);                   // 33792*768*2   = 51,904,512
  u16* xbf = (u16*)(ws + 51904512);        // 33792*256*2   = 17,301,504 (oc only now)
  u16* ows = (u16*)(ws + 69206016);        // 256*256*256*2 = 33,554,432
  u16* winb = (u16*)(ws + 102760448);      // 768*256*2     = 393,216
  u16* woutb = (u16*)(ws + 103153664);     // 256*256*2     = 131,072  (end 103,284,736)

  cvt2_kernel<<<256, 256, 0, stream>>>(w_in, w_out, winb, woutb, 49152, 16384);

  // qkv = x @ w_in^T + b_in — A read directly from f32 x, converted in staging
  // (RNE cvt_pk == f2bf, so qkv is bitwise identical to the old cvt+gemm path)
  gemm_bt_kernel<true, true><<<dim3(264, 6), 256, 0, stream>>>(x, winb, b_in, qkv, 33792, 768, 256);

  // per-(block, head) attention
  attn_kernel<<<2048, 256, 0, stream>>>(qkv, ows);

  // overlap-add + count division (commutes with the linear w_out projection)
  combine_kernel<<<4224, 256, 0, stream>>>(ows, xbf);

  // y = oc @ w_out^T + b_out
  gemm_bt_kernel<false, false><<<dim3(264, 2), 256, 0, stream>>>(xbf, woutb, b_out, y, 33792, 256, 256);
}